// Round 7
// baseline (8541.286 us; speedup 1.0000x reference)
//
#include <hip/hip_runtime.h>
#include <hip/hip_bf16.h>
#include <math.h>

#define BB 512
#define LATENT 128
#define HID 256
#define GDIM 768
#define NMAX 50
#define NHEADS 4
#define HD 64
#define NPAIRS 1225

// ---------------------------------------------------------------------------
// Tiled GEMM, double-buffered LDS: O[r][oc] = sum_k X[r][k]*W[oc][k] (+bias)
// Block tile 64x128, 256 threads, thread tile 4x8, f64 accumulate.
// XMODE: 0 = plain X; 1 = X = masked(z+pos); 2 = X f64 with row mask n<nn[b]
template<int KD, int XMODE, bool XF64, bool OF64, bool BIAS>
__global__ __launch_bounds__(256) void k_gemm4(
        const void* __restrict__ Xv, long xstride, int xzoff,
        const float* __restrict__ zin, const float* __restrict__ pin,
        const int* __restrict__ nn,
        const float* __restrict__ W, int wstride, long wzoff,
        const float* __restrict__ bias,
        void* __restrict__ Ov, long ostride, int ozoff)
{
    __shared__ double xs[2][64][17];
    __shared__ float  wsm[2][128][17];
    const int rb = blockIdx.x * 64;
    const int ob = blockIdx.y * 128;
    const int zid = blockIdx.z;
    const int tid = threadIdx.x;
    const int ty = tid >> 4, tx = tid & 15;
    const int lr  = tid >> 2;            // X tile row 0..63
    const int lk  = (tid & 3) * 4;       // X k offset 0,4,8,12
    const int lr2 = tid >> 1;            // W tile row 0..127
    const int lk2 = (tid & 1) * 8;       // W k offset 0/8
    const int xrow = rb + lr;

    bool maskv = true;
    const float* zp = nullptr; const float* pp = nullptr;
    const double* xp64 = nullptr; const float* xp32 = nullptr;
    if (XMODE == 1) {
        int b = xrow / NMAX, t = xrow % NMAX;
        maskv = t < nn[b];
        zp = zin + (size_t)b * LATENT;
        pp = pin + (size_t)t * LATENT;
    } else if (XMODE == 2) {
        int b = xrow / NMAX, t = xrow % NMAX;
        maskv = t < nn[b];
        xp64 = (const double*)Xv + (size_t)xrow * xstride + zid * (long)xzoff;
    } else {
        if (XF64) xp64 = (const double*)Xv + (size_t)xrow * xstride + zid * (long)xzoff;
        else      xp32 = (const float*)Xv + (size_t)xrow * xstride + zid * (long)xzoff;
    }
    const float* wp = W + (size_t)zid * wzoff + (size_t)(ob + lr2) * wstride + lk2;

    double xstg[4]; float wstg[8];

#define GEMM_LOAD(K0)                                                          \
    {                                                                          \
        if (XMODE == 1) {                                                      \
            _Pragma("unroll")                                                  \
            for (int u = 0; u < 4; ++u)                                        \
                xstg[u] = maskv ? (double)zp[(K0) + lk + u]                    \
                                + (double)pp[(K0) + lk + u] : 0.0;             \
        } else if (XMODE == 2) {                                               \
            _Pragma("unroll")                                                  \
            for (int u = 0; u < 4; ++u)                                        \
                xstg[u] = maskv ? xp64[(K0) + lk + u] : 0.0;                   \
        } else if (XF64) {                                                     \
            _Pragma("unroll")                                                  \
            for (int u = 0; u < 4; ++u) xstg[u] = xp64[(K0) + lk + u];         \
        } else {                                                               \
            _Pragma("unroll")                                                  \
            for (int u = 0; u < 4; ++u) xstg[u] = (double)xp32[(K0) + lk + u]; \
        }                                                                      \
        _Pragma("unroll")                                                      \
        for (int u = 0; u < 8; ++u) wstg[u] = wp[(K0) + u];                    \
    }

#define GEMM_WRITE(BUF)                                                        \
    {                                                                          \
        _Pragma("unroll")                                                      \
        for (int u = 0; u < 4; ++u) xs[(BUF)][lr][lk + u] = xstg[u];           \
        _Pragma("unroll")                                                      \
        for (int u = 0; u < 8; ++u) wsm[(BUF)][lr2][lk2 + u] = wstg[u];        \
    }

    double acc[4][8];
    #pragma unroll
    for (int i = 0; i < 4; ++i)
        #pragma unroll
        for (int j = 0; j < 8; ++j) acc[i][j] = 0.0;

    constexpr int NC = KD / 16;
    GEMM_LOAD(0);
    GEMM_WRITE(0);
    for (int c = 0; c < NC; ++c) {
        __syncthreads();
        if (c + 1 < NC) GEMM_LOAD((c + 1) * 16);
        const int bi = c & 1;
        #pragma unroll
        for (int kk = 0; kk < 16; ++kk) {
            double wv[8];
            #pragma unroll
            for (int j = 0; j < 8; ++j) wv[j] = (double)wsm[bi][j * 16 + tx][kk];
            #pragma unroll
            for (int i = 0; i < 4; ++i) {
                double xr = xs[bi][ty * 4 + i][kk];
                #pragma unroll
                for (int j = 0; j < 8; ++j) acc[i][j] += xr * wv[j];
            }
        }
        if (c + 1 < NC) GEMM_WRITE((c + 1) & 1);
    }
    #pragma unroll
    for (int i = 0; i < 4; ++i) {
        size_t row = rb + ty * 4 + i;
        #pragma unroll
        for (int j = 0; j < 8; ++j) {
            int ocg = ob + j * 16 + tx;
            double v = acc[i][j];
            if (BIAS) v += (double)bias[ocg];
            size_t o = row * ostride + (size_t)zid * ozoff + ocg;
            if (OF64) ((double*)Ov)[o] = v;
            else      ((float*)Ov)[o] = (float)v;
        }
    }
#undef GEMM_LOAD
#undef GEMM_WRITE
}

// ---------------------------------------------------------------------------
// pack w_hh f32 [768][256] -> wRZ float2 [k][f] (r,z) and wN float [k][f]
__global__ __launch_bounds__(256) void k_pack_bat(
        const float* __restrict__ whh, float2* __restrict__ wRZ,
        float* __restrict__ wN)
{
    int k = blockIdx.x, f = threadIdx.x;
    float r = whh[(size_t)(0 * HID + f) * HID + k];
    float zz = whh[(size_t)(1 * HID + f) * HID + k];
    float n = whh[(size_t)(2 * HID + f) * HID + k];
    wRZ[(size_t)k * HID + f] = make_float2(r, zz);
    wN[(size_t)k * HID + f] = n;
}

// ---------------------------------------------------------------------------
// Persistent batch-sliced GRU: grid 256 x 512 threads, block owns 2 batches,
// h in LDS, no inter-block comms. Weights stream from L2 with explicit
// register double-buffered prefetch (16-k chunks) to hide L2 latency.
// Summation order identical to R6 (bitwise-same results).
__global__ __launch_bounds__(512) void k_gru_batch2(
        const double* __restrict__ xg, double* __restrict__ hout,
        const float2* __restrict__ wRZ, const float* __restrict__ wN,
        const float* __restrict__ bhh)
{
    const int tid = threadIdx.x;
    const int f  = tid & 255;
    const int kq = tid >> 8;             // 0/1
    const int b0 = blockIdx.x * 2;

    __shared__ double hs[HID][2];        // [k][batch]
    __shared__ double red[HID][6];       // kq=1 partials

    { double* hf = &hs[0][0]; hf[tid] = 0.0; }

    double br = 0, bz = 0, bn = 0;
    if (!kq) {
        br = (double)bhh[f]; bz = (double)bhh[HID + f]; bn = (double)bhh[2 * HID + f];
    }
    const float2* wrz = wRZ + (size_t)(kq * 128) * HID + f;
    const float*  wn  = wN  + (size_t)(kq * 128) * HID + f;
    const double* x0base = xg + (size_t)b0 * NMAX * GDIM + f;
    const double* x1base = xg + (size_t)(b0 + 1) * NMAX * GDIM + f;
    double* h0out = hout + (size_t)b0 * NMAX * HID + f;
    double* h1out = hout + (size_t)(b0 + 1) * NMAX * HID + f;
    const int kbase = kq * 128;

    __syncthreads();

    float2 pa_rz[16]; float pa_n[16];
    float2 pb_rz[16]; float pb_n[16];

#define LOADW(R, N, C)                                                         \
    { _Pragma("unroll")                                                        \
      for (int u = 0; u < 16; ++u) {                                           \
          R[u] = wrz[(size_t)((C) * 16 + u) * HID];                            \
          N[u] = wn[(size_t)((C) * 16 + u) * HID];                             \
      } }
#define MACW(R, N, C)                                                          \
    { _Pragma("unroll")                                                        \
      for (int u = 0; u < 16; ++u) {                                           \
          int k = kbase + (C) * 16 + u;                                        \
          double wrd = (double)R[u].x, wzd = (double)R[u].y, wnd = (double)N[u];\
          double h0k = hs[k][0], h1k = hs[k][1];                               \
          ar0 += h0k * wrd; az0 += h0k * wzd; an0 += h0k * wnd;                \
          ar1 += h1k * wrd; az1 += h1k * wzd; an1 += h1k * wnd;                \
      } }

    for (int t = 0; t < NMAX; ++t) {
        // issue xg loads early (kq0 only) — consumed after the MAC loop
        double xr0 = 0, xz0 = 0, xn0 = 0, xr1 = 0, xz1 = 0, xn1 = 0;
        if (!kq) {
            const double* x0 = x0base + (size_t)t * GDIM;
            const double* x1 = x1base + (size_t)t * GDIM;
            xr0 = x0[0]; xz0 = x0[HID]; xn0 = x0[2 * HID];
            xr1 = x1[0]; xz1 = x1[HID]; xn1 = x1[2 * HID];
        }

        double ar0 = 0, az0 = 0, an0 = 0, ar1 = 0, az1 = 0, an1 = 0;
        LOADW(pa_rz, pa_n, 0);
        for (int c = 0; c < 8; c += 2) {
            LOADW(pb_rz, pb_n, c + 1);
            MACW(pa_rz, pa_n, c);
            if (c + 2 < 8) LOADW(pa_rz, pa_n, c + 2);
            MACW(pb_rz, pb_n, c + 1);
        }

        if (kq) {
            red[f][0] = ar0; red[f][1] = az0; red[f][2] = an0;
            red[f][3] = ar1; red[f][4] = az1; red[f][5] = an1;
        }
        __syncthreads();
        if (!kq) {
            ar0 += red[f][0]; az0 += red[f][1]; an0 += red[f][2];
            ar1 += red[f][3]; az1 += red[f][4]; an1 += red[f][5];
            double hp0 = hs[f][0], hp1 = hs[f][1];
            double rg0 = 1.0 / (1.0 + exp(-(xr0 + ar0 + br)));
            double zg0 = 1.0 / (1.0 + exp(-(xz0 + az0 + bz)));
            double ng0 = tanh(xn0 + rg0 * (an0 + bn));
            double h0n = (1.0 - zg0) * ng0 + zg0 * hp0;
            double rg1 = 1.0 / (1.0 + exp(-(xr1 + ar1 + br)));
            double zg1 = 1.0 / (1.0 + exp(-(xz1 + az1 + bz)));
            double ng1 = tanh(xn1 + rg1 * (an1 + bn));
            double h1n = (1.0 - zg1) * ng1 + zg1 * hp1;
            hs[f][0] = h0n; hs[f][1] = h1n;
            h0out[(size_t)t * HID] = h0n;
            h1out[(size_t)t * HID] = h1n;
        }
        __syncthreads();
    }
#undef LOADW
#undef MACW
}

// ---------------------------------------------------------------------------
// WQ[g][h] = sum_o attn_in_w[g][o] * proj[o][h]   (768x256 f32)
__global__ __launch_bounds__(256) void k_wq(
        const float* __restrict__ aiw, const float* __restrict__ proj,
        float* __restrict__ WQ)
{
    __shared__ float arow[HID];
    int g = blockIdx.x, h = threadIdx.x;
    arow[h] = aiw[(size_t)g * HID + h];
    __syncthreads();
    double acc = 0.0;
    for (int o = 0; o < HID; ++o) acc += (double)arow[o] * (double)proj[(size_t)o * HID + h];
    WQ[(size_t)g * HID + h] = (float)acc;
}

// M[h][k][d] = sum_m wo[m][h*64+d] * w1[k][m]   (4x256x64 f32)
__global__ __launch_bounds__(256) void k_m(
        const float* __restrict__ wo, const float* __restrict__ w1,
        float* __restrict__ M)
{
    __shared__ float w1row[HID];
    int k = blockIdx.x, hd = threadIdx.x;
    w1row[hd] = w1[(size_t)k * HID + hd];
    __syncthreads();
    double acc = 0.0;
    for (int m = 0; m < HID; ++m) acc += (double)w1row[m] * (double)wo[(size_t)m * HID + hd];
    M[(((size_t)(hd >> 6)) * HID + k) * HD + (hd & 63)] = (float)acc;
}

// c[k] = sum_m attn_out_b[m]*mlp_w1[k,m] + mlp_b1[k]
__global__ void k_const(const float* __restrict__ ob, const float* __restrict__ w1,
                        const float* __restrict__ b1, double* __restrict__ c)
{
    int k = threadIdx.x;
    double acc = 0.0;
    for (int m = 0; m < HID; ++m) acc += (double)ob[m] * (double)w1[k * HID + m];
    c[k] = acc + (double)b1[k];
}

// ---------------------------------------------------------------------------
// Pairs: block per (b,i); wave per j (stride 4). G unified [row][h*256+k].
__global__ __launch_bounds__(256) void k_pairs3(
        const float* __restrict__ QKV, const float* __restrict__ G,
        const double* __restrict__ c,
        const int* __restrict__ nn, const float* __restrict__ gum,
        const float* __restrict__ w2, const float* __restrict__ b2,
        float* __restrict__ adj)
{
    const int bi = blockIdx.x;
    const int b = bi / (NMAX - 1);
    const int i = bi % (NMAX - 1);
    const int nnb = nn[b];
    if (i >= nnb - 1) return;
    const int tid = threadIdx.x;
    const int lane = tid & 63;
    const int wave = tid >> 6;
    const size_t rowi = (size_t)b * NMAX + i;

    double cw[4], w2r[4];
    float gir[4][4];
    #pragma unroll
    for (int q = 0; q < 4; ++q) {
        int k = lane + 64 * q;
        cw[q] = c[k];
        w2r[q] = (double)w2[k] - (double)w2[HID + k];
        #pragma unroll
        for (int h = 0; h < 4; ++h) gir[q][h] = G[rowi * 1024 + h * HID + k];
    }
    const int sh = lane >> 4, sd = (lane & 15) * 4;
    const float4 qv  = *(const float4*)&QKV[rowi * GDIM + sh * HD + sd];
    const float4 kv0 = *(const float4*)&QKV[rowi * GDIM + HID + sh * HD + sd];
    double s0 = (double)qv.x * kv0.x + (double)qv.y * kv0.y
              + (double)qv.z * kv0.z + (double)qv.w * kv0.w;
    #pragma unroll
    for (int m = 1; m < 16; m <<= 1) s0 += __shfl_xor(s0, m, 64);
    s0 *= 0.125;
    const double b2d = (double)b2[0] - (double)b2[1];

    for (int j = i + 1 + wave; j < nnb; j += 4) {
        const size_t rowj = (size_t)b * NMAX + j;
        const float4 kv = *(const float4*)&QKV[rowj * GDIM + HID + sh * HD + sd];
        double s1 = (double)qv.x * kv.x + (double)qv.y * kv.y
                  + (double)qv.z * kv.z + (double)qv.w * kv.w;
        #pragma unroll
        for (int m = 1; m < 16; m <<= 1) s1 += __shfl_xor(s1, m, 64);
        s1 *= 0.125;
        double mx = fmax(s0, s1);
        double e0 = exp(s0 - mx), e1 = exp(s1 - mx);
        double inv = 1.0 / (e0 + e1);
        double a0 = e0 * inv, a1 = e1 * inv;
        double a0h[4], a1h[4];
        #pragma unroll
        for (int h = 0; h < 4; ++h) {
            a0h[h] = __shfl(a0, h * 16, 64);
            a1h[h] = __shfl(a1, h * 16, 64);
        }
        double dsum = 0.0;
        #pragma unroll
        for (int q = 0; q < 4; ++q) {
            int k = lane + 64 * q;
            double pre = cw[q];
            #pragma unroll
            for (int h = 0; h < 4; ++h)
                pre += a0h[h] * (double)gir[q][h]
                     + a1h[h] * (double)G[rowj * 1024 + h * HID + k];
            if (pre > 0.0) dsum += pre * w2r[q];
        }
        #pragma unroll
        for (int m = 1; m < 64; m <<= 1) dsum += __shfl_xor(dsum, m, 64);
        if (lane == 0) {
            int p_idx = i * (2 * NMAX - i - 1) / 2 + (j - i - 1);
            const float* gp = gum + ((size_t)b * NPAIRS + p_idx) * 2;
            double d = dsum + b2d + (double)gp[0] - (double)gp[1];
            if (d >= 0.0) {
                adj[(size_t)b * NMAX * NMAX + i * NMAX + j] = 1.0f;
                adj[(size_t)b * NMAX * NMAX + j * NMAX + i] = 1.0f;
            }
        }
    }
}

__global__ void k_ws_too_small(float* adj) { adj[0] = 2.0f; }

// ---------------------------------------------------------------------------
extern "C" void kernel_launch(void* const* d_in, const int* in_sizes, int n_in,
                              void* d_out, int out_size, void* d_ws, size_t ws_size,
                              hipStream_t stream)
{
    const float* z          = (const float*)d_in[0];
    const int*   nn         = (const int*)d_in[1];
    const float* pos        = (const float*)d_in[3];
    const float* w_ih0      = (const float*)d_in[4];
    const float* w_hh0      = (const float*)d_in[5];
    const float* b_ih0      = (const float*)d_in[6];
    const float* b_hh0      = (const float*)d_in[7];
    const float* w_ih1      = (const float*)d_in[8];
    const float* w_hh1      = (const float*)d_in[9];
    const float* b_ih1      = (const float*)d_in[10];
    const float* b_hh1      = (const float*)d_in[11];
    const float* proj       = (const float*)d_in[12];
    const float* attn_in_w  = (const float*)d_in[13];
    const float* attn_in_b  = (const float*)d_in[14];
    const float* attn_out_w = (const float*)d_in[15];
    const float* attn_out_b = (const float*)d_in[16];
    const float* mlp_w1     = (const float*)d_in[17];
    const float* mlp_b1     = (const float*)d_in[18];
    const float* mlp_w2     = (const float*)d_in[19];
    const float* mlp_b2     = (const float*)d_in[20];
    const float* gum        = (const float*)d_in[21];

    float* adj = (float*)d_out;
    hipMemsetAsync(adj, 0, (size_t)out_size * sizeof(float), stream);

    const size_t NEED = 262144000;
    if (ws_size < NEED) { hipLaunchKernelGGL(k_ws_too_small, dim3(1), dim3(1), 0, stream, adj); return; }

    // Region map (phase-aliased, single stream => sequential hazards OK):
    //  A [0,157286400):          xg f64 | post-GRU: qkv f32 @0, G f32 @78643200
    //  B [157286400,209715200):  h0 f64 | post-xg1: wRZ1 @B, wN1 @B+524288
    //                            | post-G-spill tail: WQ @183500800, M @184287232,
    //                              cbf @184549376
    //  C [209715200,262144000):  wRZ0 @C, wN0 @C+524288 | post-gru0: h1 f64 @C
    char* ws = (char*)d_ws;
    const size_t Boff = 157286400, Coff = 209715200;
    double* xg   = (double*)(ws);
    double* h0   = (double*)(ws + Boff);
    double* h1   = (double*)(ws + Coff);
    float2* wRZ0 = (float2*)(ws + Coff);
    float*  wN0  = (float*)(ws + Coff + 524288);
    float2* wRZ1 = (float2*)(ws + Boff);
    float*  wN1  = (float*)(ws + Boff + 524288);
    float*  qkv  = (float*)(ws);
    float*  G    = (float*)(ws + 78643200);
    float*  WQ   = (float*)(ws + 183500800);
    float*  M    = (float*)(ws + 184287232);
    double* cbf  = (double*)(ws + 184549376);

    // 1) fused seq construction + layer-0 input gates
    hipLaunchKernelGGL((k_gemm4<LATENT, 1, true, true, true>), dim3(400, 6), dim3(256), 0, stream,
                       nullptr, 0L, 0, z, pos, nn, w_ih0, LATENT, 0L, b_ih0,
                       (void*)xg, (long)GDIM, 0);
    // 2) GRU layer 0 (persistent, batch-sliced, reg-prefetched weights)
    hipLaunchKernelGGL(k_pack_bat, dim3(256), dim3(256), 0, stream, w_hh0, wRZ0, wN0);
    hipLaunchKernelGGL(k_gru_batch2, dim3(256), dim3(512), 0, stream,
                       xg, h0, wRZ0, wN0, b_hh0);
    // 3) layer-1 input gates
    hipLaunchKernelGGL((k_gemm4<HID, 0, true, true, true>), dim3(400, 6), dim3(256), 0, stream,
                       (const void*)h0, (long)HID, 0, nullptr, nullptr, nn,
                       w_ih1, HID, 0L, b_ih1, (void*)xg, (long)GDIM, 0);
    // 4) GRU layer 1 (weights into dead h0 region)
    hipLaunchKernelGGL(k_pack_bat, dim3(256), dim3(256), 0, stream, w_hh1, wRZ1, wN1);
    hipLaunchKernelGGL(k_gru_batch2, dim3(256), dim3(512), 0, stream,
                       xg, h1, wRZ1, wN1, b_hh1);
    // 5) fused (proj @ attn_in_w), then masked qkv directly from h1
    hipLaunchKernelGGL(k_wq, dim3(768), dim3(256), 0, stream, attn_in_w, proj, WQ);
    hipLaunchKernelGGL((k_gemm4<HID, 2, true, false, true>), dim3(400, 6), dim3(256), 0, stream,
                       (const void*)h1, (long)HID, 0, nullptr, nullptr, nn,
                       WQ, HID, 0L, attn_in_b, (void*)qkv, (long)GDIM, 0);
    // 6) M precompute + single fused G GEMM (grid.z = head)
    hipLaunchKernelGGL(k_m, dim3(256), dim3(256), 0, stream, attn_out_w, mlp_w1, M);
    hipLaunchKernelGGL(k_const, dim3(1), dim3(256), 0, stream, attn_out_b, mlp_w1, mlp_b1, cbf);
    hipLaunchKernelGGL((k_gemm4<HD, 0, false, false, false>), dim3(400, 2, 4), dim3(256), 0, stream,
                       (const void*)(qkv + 2 * HID), (long)GDIM, HD, nullptr, nullptr, nn,
                       M, HD, (long)(HID * HD), (const float*)nullptr,
                       (void*)G, 1024L, HID);
    // 7) pairs
    hipLaunchKernelGGL(k_pairs3, dim3(BB * (NMAX - 1)), dim3(256), 0, stream,
                       qkv, G, cbf, nn, gum, mlp_w2, mlp_b2, adj);
}

// Round 8
// 8060.986 us; speedup vs baseline: 1.0596x; 1.0596x over previous
//
#include <hip/hip_runtime.h>
#include <hip/hip_bf16.h>
#include <math.h>

#define BB 512
#define LATENT 128
#define HID 256
#define GDIM 768
#define NMAX 50
#define NHEADS 4
#define HD 64
#define NPAIRS 1225

// ---------------------------------------------------------------------------
// Tiled GEMM, double-buffered LDS: O[r][oc] = sum_k X[r][k]*W[oc][k] (+bias)
// Block tile 64x128, 256 threads, thread tile 4x8, f64 accumulate.
// XMODE: 0 = plain X; 1 = X = masked(z+pos); 2 = X f64 with row mask n<nn[b]
template<int KD, int XMODE, bool XF64, bool OF64, bool BIAS>
__global__ __launch_bounds__(256) void k_gemm4(
        const void* __restrict__ Xv, long xstride, int xzoff,
        const float* __restrict__ zin, const float* __restrict__ pin,
        const int* __restrict__ nn,
        const float* __restrict__ W, int wstride, long wzoff,
        const float* __restrict__ bias,
        void* __restrict__ Ov, long ostride, int ozoff)
{
    __shared__ double xs[2][64][17];
    __shared__ float  wsm[2][128][17];
    const int rb = blockIdx.x * 64;
    const int ob = blockIdx.y * 128;
    const int zid = blockIdx.z;
    const int tid = threadIdx.x;
    const int ty = tid >> 4, tx = tid & 15;
    const int lr  = tid >> 2;            // X tile row 0..63
    const int lk  = (tid & 3) * 4;       // X k offset 0,4,8,12
    const int lr2 = tid >> 1;            // W tile row 0..127
    const int lk2 = (tid & 1) * 8;       // W k offset 0/8
    const int xrow = rb + lr;

    bool maskv = true;
    const float* zp = nullptr; const float* pp = nullptr;
    const double* xp64 = nullptr; const float* xp32 = nullptr;
    if (XMODE == 1) {
        int b = xrow / NMAX, t = xrow % NMAX;
        maskv = t < nn[b];
        zp = zin + (size_t)b * LATENT;
        pp = pin + (size_t)t * LATENT;
    } else if (XMODE == 2) {
        int b = xrow / NMAX, t = xrow % NMAX;
        maskv = t < nn[b];
        xp64 = (const double*)Xv + (size_t)xrow * xstride + zid * (long)xzoff;
    } else {
        if (XF64) xp64 = (const double*)Xv + (size_t)xrow * xstride + zid * (long)xzoff;
        else      xp32 = (const float*)Xv + (size_t)xrow * xstride + zid * (long)xzoff;
    }
    const float* wp = W + (size_t)zid * wzoff + (size_t)(ob + lr2) * wstride + lk2;

    double xstg[4]; float wstg[8];

#define GEMM_LOAD(K0)                                                          \
    {                                                                          \
        if (XMODE == 1) {                                                      \
            _Pragma("unroll")                                                  \
            for (int u = 0; u < 4; ++u)                                        \
                xstg[u] = maskv ? (double)zp[(K0) + lk + u]                    \
                                + (double)pp[(K0) + lk + u] : 0.0;             \
        } else if (XMODE == 2) {                                               \
            _Pragma("unroll")                                                  \
            for (int u = 0; u < 4; ++u)                                        \
                xstg[u] = maskv ? xp64[(K0) + lk + u] : 0.0;                   \
        } else if (XF64) {                                                     \
            _Pragma("unroll")                                                  \
            for (int u = 0; u < 4; ++u) xstg[u] = xp64[(K0) + lk + u];         \
        } else {                                                               \
            _Pragma("unroll")                                                  \
            for (int u = 0; u < 4; ++u) xstg[u] = (double)xp32[(K0) + lk + u]; \
        }                                                                      \
        _Pragma("unroll")                                                      \
        for (int u = 0; u < 8; ++u) wstg[u] = wp[(K0) + u];                    \
    }

#define GEMM_WRITE(BUF)                                                        \
    {                                                                          \
        _Pragma("unroll")                                                      \
        for (int u = 0; u < 4; ++u) xs[(BUF)][lr][lk + u] = xstg[u];           \
        _Pragma("unroll")                                                      \
        for (int u = 0; u < 8; ++u) wsm[(BUF)][lr2][lk2 + u] = wstg[u];        \
    }

    double acc[4][8];
    #pragma unroll
    for (int i = 0; i < 4; ++i)
        #pragma unroll
        for (int j = 0; j < 8; ++j) acc[i][j] = 0.0;

    constexpr int NC = KD / 16;
    GEMM_LOAD(0);
    GEMM_WRITE(0);
    for (int c = 0; c < NC; ++c) {
        __syncthreads();
        if (c + 1 < NC) GEMM_LOAD((c + 1) * 16);
        const int bi = c & 1;
        #pragma unroll
        for (int kk = 0; kk < 16; ++kk) {
            double wv[8];
            #pragma unroll
            for (int j = 0; j < 8; ++j) wv[j] = (double)wsm[bi][j * 16 + tx][kk];
            #pragma unroll
            for (int i = 0; i < 4; ++i) {
                double xr = xs[bi][ty * 4 + i][kk];
                #pragma unroll
                for (int j = 0; j < 8; ++j) acc[i][j] += xr * wv[j];
            }
        }
        if (c + 1 < NC) GEMM_WRITE((c + 1) & 1);
    }
    #pragma unroll
    for (int i = 0; i < 4; ++i) {
        size_t row = rb + ty * 4 + i;
        #pragma unroll
        for (int j = 0; j < 8; ++j) {
            int ocg = ob + j * 16 + tx;
            double v = acc[i][j];
            if (BIAS) v += (double)bias[ocg];
            size_t o = row * ostride + (size_t)zid * ozoff + ocg;
            if (OF64) ((double*)Ov)[o] = v;
            else      ((float*)Ov)[o] = (float)v;
        }
    }
#undef GEMM_LOAD
#undef GEMM_WRITE
}

// ---------------------------------------------------------------------------
// pack w_hh f32 [768][256] -> wRZ float2 [k][f] (r,z) and wN float [k][f]
__global__ __launch_bounds__(256) void k_pack_bat(
        const float* __restrict__ whh, float2* __restrict__ wRZ,
        float* __restrict__ wN)
{
    int k = blockIdx.x, f = threadIdx.x;
    float r = whh[(size_t)(0 * HID + f) * HID + k];
    float zz = whh[(size_t)(1 * HID + f) * HID + k];
    float n = whh[(size_t)(2 * HID + f) * HID + k];
    wRZ[(size_t)k * HID + f] = make_float2(r, zz);
    wN[(size_t)k * HID + f] = n;
}

// ---------------------------------------------------------------------------
// Persistent batch-sliced GRU: grid 256 x 512 threads, block owns 2 batches,
// h in LDS, no inter-block comms. Weights stream from L2 with register
// double-buffered prefetch, depth 8 (fits in VGPR budget — no spill).
// __launch_bounds__(512, 2): 2 waves/EU = this kernel's natural occupancy
// (1 block/CU), raises VGPR cap to 256 so the ~110 VGPRs used don't spill.
// Summation order identical to R6 (bitwise-same results).
__global__ __launch_bounds__(512, 2) void k_gru_batch3(
        const double* __restrict__ xg, double* __restrict__ hout,
        const float2* __restrict__ wRZ, const float* __restrict__ wN,
        const float* __restrict__ bhh)
{
    const int tid = threadIdx.x;
    const int f  = tid & 255;
    const int kq = tid >> 8;             // 0/1
    const int b0 = blockIdx.x * 2;

    __shared__ double hs[HID][2];        // [k][batch]
    __shared__ double red[HID][6];       // kq=1 partials

    { double* hf = &hs[0][0]; hf[tid] = 0.0; }

    double br = 0, bz = 0, bn = 0;
    if (!kq) {
        br = (double)bhh[f]; bz = (double)bhh[HID + f]; bn = (double)bhh[2 * HID + f];
    }
    const float2* wrz = wRZ + (size_t)(kq * 128) * HID + f;
    const float*  wn  = wN  + (size_t)(kq * 128) * HID + f;
    const double* x0base = xg + (size_t)b0 * NMAX * GDIM + f;
    const double* x1base = xg + (size_t)(b0 + 1) * NMAX * GDIM + f;
    double* h0out = hout + (size_t)b0 * NMAX * HID + f;
    double* h1out = hout + (size_t)(b0 + 1) * NMAX * HID + f;
    const int kbase = kq * 128;

    __syncthreads();

    float2 pa_rz[8]; float pa_n[8];
    float2 pb_rz[8]; float pb_n[8];

#define LOADW(R, N, C)                                                         \
    { _Pragma("unroll")                                                        \
      for (int u = 0; u < 8; ++u) {                                            \
          R[u] = wrz[(size_t)((C) * 8 + u) * HID];                             \
          N[u] = wn[(size_t)((C) * 8 + u) * HID];                              \
      } }
#define MACW(R, N, C)                                                          \
    { _Pragma("unroll")                                                        \
      for (int u = 0; u < 8; ++u) {                                            \
          int k = kbase + (C) * 8 + u;                                         \
          double wrd = (double)R[u].x, wzd = (double)R[u].y, wnd = (double)N[u];\
          double h0k = hs[k][0], h1k = hs[k][1];                               \
          ar0 += h0k * wrd; az0 += h0k * wzd; an0 += h0k * wnd;                \
          ar1 += h1k * wrd; az1 += h1k * wzd; an1 += h1k * wnd;                \
      } }

    for (int t = 0; t < NMAX; ++t) {
        // issue xg loads early (kq0 only) — consumed after the MAC loop
        double xr0 = 0, xz0 = 0, xn0 = 0, xr1 = 0, xz1 = 0, xn1 = 0;
        if (!kq) {
            const double* x0 = x0base + (size_t)t * GDIM;
            const double* x1 = x1base + (size_t)t * GDIM;
            xr0 = x0[0]; xz0 = x0[HID]; xn0 = x0[2 * HID];
            xr1 = x1[0]; xz1 = x1[HID]; xn1 = x1[2 * HID];
        }

        double ar0 = 0, az0 = 0, an0 = 0, ar1 = 0, az1 = 0, an1 = 0;
        LOADW(pa_rz, pa_n, 0);
        #pragma unroll
        for (int c = 0; c < 16; c += 2) {
            LOADW(pb_rz, pb_n, c + 1);
            MACW(pa_rz, pa_n, c);
            if (c + 2 < 16) LOADW(pa_rz, pa_n, c + 2);
            MACW(pb_rz, pb_n, c + 1);
        }

        if (kq) {
            red[f][0] = ar0; red[f][1] = az0; red[f][2] = an0;
            red[f][3] = ar1; red[f][4] = az1; red[f][5] = an1;
        }
        __syncthreads();
        if (!kq) {
            ar0 += red[f][0]; az0 += red[f][1]; an0 += red[f][2];
            ar1 += red[f][3]; az1 += red[f][4]; an1 += red[f][5];
            double hp0 = hs[f][0], hp1 = hs[f][1];
            double rg0 = 1.0 / (1.0 + exp(-(xr0 + ar0 + br)));
            double zg0 = 1.0 / (1.0 + exp(-(xz0 + az0 + bz)));
            double ng0 = tanh(xn0 + rg0 * (an0 + bn));
            double h0n = (1.0 - zg0) * ng0 + zg0 * hp0;
            double rg1 = 1.0 / (1.0 + exp(-(xr1 + ar1 + br)));
            double zg1 = 1.0 / (1.0 + exp(-(xz1 + az1 + bz)));
            double ng1 = tanh(xn1 + rg1 * (an1 + bn));
            double h1n = (1.0 - zg1) * ng1 + zg1 * hp1;
            hs[f][0] = h0n; hs[f][1] = h1n;
            h0out[(size_t)t * HID] = h0n;
            h1out[(size_t)t * HID] = h1n;
        }
        __syncthreads();
    }
#undef LOADW
#undef MACW
}

// ---------------------------------------------------------------------------
// WQ[g][h] = sum_o attn_in_w[g][o] * proj[o][h]   (768x256 f32)
__global__ __launch_bounds__(256) void k_wq(
        const float* __restrict__ aiw, const float* __restrict__ proj,
        float* __restrict__ WQ)
{
    __shared__ float arow[HID];
    int g = blockIdx.x, h = threadIdx.x;
    arow[h] = aiw[(size_t)g * HID + h];
    __syncthreads();
    double acc = 0.0;
    for (int o = 0; o < HID; ++o) acc += (double)arow[o] * (double)proj[(size_t)o * HID + h];
    WQ[(size_t)g * HID + h] = (float)acc;
}

// M[h][k][d] = sum_m wo[m][h*64+d] * w1[k][m]   (4x256x64 f32)
__global__ __launch_bounds__(256) void k_m(
        const float* __restrict__ wo, const float* __restrict__ w1,
        float* __restrict__ M)
{
    __shared__ float w1row[HID];
    int k = blockIdx.x, hd = threadIdx.x;
    w1row[hd] = w1[(size_t)k * HID + hd];
    __syncthreads();
    double acc = 0.0;
    for (int m = 0; m < HID; ++m) acc += (double)w1row[m] * (double)wo[(size_t)m * HID + hd];
    M[(((size_t)(hd >> 6)) * HID + k) * HD + (hd & 63)] = (float)acc;
}

// c[k] = sum_m attn_out_b[m]*mlp_w1[k,m] + mlp_b1[k]
__global__ void k_const(const float* __restrict__ ob, const float* __restrict__ w1,
                        const float* __restrict__ b1, double* __restrict__ c)
{
    int k = threadIdx.x;
    double acc = 0.0;
    for (int m = 0; m < HID; ++m) acc += (double)ob[m] * (double)w1[k * HID + m];
    c[k] = acc + (double)b1[k];
}

// ---------------------------------------------------------------------------
// Pairs: block per (b,i); wave per j (stride 4). G unified [row][h*256+k].
__global__ __launch_bounds__(256) void k_pairs3(
        const float* __restrict__ QKV, const float* __restrict__ G,
        const double* __restrict__ c,
        const int* __restrict__ nn, const float* __restrict__ gum,
        const float* __restrict__ w2, const float* __restrict__ b2,
        float* __restrict__ adj)
{
    const int bi = blockIdx.x;
    const int b = bi / (NMAX - 1);
    const int i = bi % (NMAX - 1);
    const int nnb = nn[b];
    if (i >= nnb - 1) return;
    const int tid = threadIdx.x;
    const int lane = tid & 63;
    const int wave = tid >> 6;
    const size_t rowi = (size_t)b * NMAX + i;

    double cw[4], w2r[4];
    float gir[4][4];
    #pragma unroll
    for (int q = 0; q < 4; ++q) {
        int k = lane + 64 * q;
        cw[q] = c[k];
        w2r[q] = (double)w2[k] - (double)w2[HID + k];
        #pragma unroll
        for (int h = 0; h < 4; ++h) gir[q][h] = G[rowi * 1024 + h * HID + k];
    }
    const int sh = lane >> 4, sd = (lane & 15) * 4;
    const float4 qv  = *(const float4*)&QKV[rowi * GDIM + sh * HD + sd];
    const float4 kv0 = *(const float4*)&QKV[rowi * GDIM + HID + sh * HD + sd];
    double s0 = (double)qv.x * kv0.x + (double)qv.y * kv0.y
              + (double)qv.z * kv0.z + (double)qv.w * kv0.w;
    #pragma unroll
    for (int m = 1; m < 16; m <<= 1) s0 += __shfl_xor(s0, m, 64);
    s0 *= 0.125;
    const double b2d = (double)b2[0] - (double)b2[1];

    for (int j = i + 1 + wave; j < nnb; j += 4) {
        const size_t rowj = (size_t)b * NMAX + j;
        const float4 kv = *(const float4*)&QKV[rowj * GDIM + HID + sh * HD + sd];
        double s1 = (double)qv.x * kv.x + (double)qv.y * kv.y
                  + (double)qv.z * kv.z + (double)qv.w * kv.w;
        #pragma unroll
        for (int m = 1; m < 16; m <<= 1) s1 += __shfl_xor(s1, m, 64);
        s1 *= 0.125;
        double mx = fmax(s0, s1);
        double e0 = exp(s0 - mx), e1 = exp(s1 - mx);
        double inv = 1.0 / (e0 + e1);
        double a0 = e0 * inv, a1 = e1 * inv;
        double a0h[4], a1h[4];
        #pragma unroll
        for (int h = 0; h < 4; ++h) {
            a0h[h] = __shfl(a0, h * 16, 64);
            a1h[h] = __shfl(a1, h * 16, 64);
        }
        double dsum = 0.0;
        #pragma unroll
        for (int q = 0; q < 4; ++q) {
            int k = lane + 64 * q;
            double pre = cw[q];
            #pragma unroll
            for (int h = 0; h < 4; ++h)
                pre += a0h[h] * (double)gir[q][h]
                     + a1h[h] * (double)G[rowj * 1024 + h * HID + k];
            if (pre > 0.0) dsum += pre * w2r[q];
        }
        #pragma unroll
        for (int m = 1; m < 64; m <<= 1) dsum += __shfl_xor(dsum, m, 64);
        if (lane == 0) {
            int p_idx = i * (2 * NMAX - i - 1) / 2 + (j - i - 1);
            const float* gp = gum + ((size_t)b * NPAIRS + p_idx) * 2;
            double d = dsum + b2d + (double)gp[0] - (double)gp[1];
            if (d >= 0.0) {
                adj[(size_t)b * NMAX * NMAX + i * NMAX + j] = 1.0f;
                adj[(size_t)b * NMAX * NMAX + j * NMAX + i] = 1.0f;
            }
        }
    }
}

__global__ void k_ws_too_small(float* adj) { adj[0] = 2.0f; }

// ---------------------------------------------------------------------------
extern "C" void kernel_launch(void* const* d_in, const int* in_sizes, int n_in,
                              void* d_out, int out_size, void* d_ws, size_t ws_size,
                              hipStream_t stream)
{
    const float* z          = (const float*)d_in[0];
    const int*   nn         = (const int*)d_in[1];
    const float* pos        = (const float*)d_in[3];
    const float* w_ih0      = (const float*)d_in[4];
    const float* w_hh0      = (const float*)d_in[5];
    const float* b_ih0      = (const float*)d_in[6];
    const float* b_hh0      = (const float*)d_in[7];
    const float* w_ih1      = (const float*)d_in[8];
    const float* w_hh1      = (const float*)d_in[9];
    const float* b_ih1      = (const float*)d_in[10];
    const float* b_hh1      = (const float*)d_in[11];
    const float* proj       = (const float*)d_in[12];
    const float* attn_in_w  = (const float*)d_in[13];
    const float* attn_in_b  = (const float*)d_in[14];
    const float* attn_out_w = (const float*)d_in[15];
    const float* attn_out_b = (const float*)d_in[16];
    const float* mlp_w1     = (const float*)d_in[17];
    const float* mlp_b1     = (const float*)d_in[18];
    const float* mlp_w2     = (const float*)d_in[19];
    const float* mlp_b2     = (const float*)d_in[20];
    const float* gum        = (const float*)d_in[21];

    float* adj = (float*)d_out;
    hipMemsetAsync(adj, 0, (size_t)out_size * sizeof(float), stream);

    const size_t NEED = 262144000;
    if (ws_size < NEED) { hipLaunchKernelGGL(k_ws_too_small, dim3(1), dim3(1), 0, stream, adj); return; }

    // Region map (phase-aliased, single stream => sequential hazards OK):
    //  A [0,157286400):          xg f64 | post-GRU: qkv f32 @0, G f32 @78643200
    //  B [157286400,209715200):  h0 f64 | post-xg1: wRZ1 @B, wN1 @B+524288
    //                            | post-G-spill tail: WQ @183500800, M @184287232,
    //                              cbf @184549376
    //  C [209715200,262144000):  wRZ0 @C, wN0 @C+524288 | post-gru0: h1 f64 @C
    char* ws = (char*)d_ws;
    const size_t Boff = 157286400, Coff = 209715200;
    double* xg   = (double*)(ws);
    double* h0   = (double*)(ws + Boff);
    double* h1   = (double*)(ws + Coff);
    float2* wRZ0 = (float2*)(ws + Coff);
    float*  wN0  = (float*)(ws + Coff + 524288);
    float2* wRZ1 = (float2*)(ws + Boff);
    float*  wN1  = (float*)(ws + Boff + 524288);
    float*  qkv  = (float*)(ws);
    float*  G    = (float*)(ws + 78643200);
    float*  WQ   = (float*)(ws + 183500800);
    float*  M    = (float*)(ws + 184287232);
    double* cbf  = (double*)(ws + 184549376);

    // 1) fused seq construction + layer-0 input gates
    hipLaunchKernelGGL((k_gemm4<LATENT, 1, true, true, true>), dim3(400, 6), dim3(256), 0, stream,
                       nullptr, 0L, 0, z, pos, nn, w_ih0, LATENT, 0L, b_ih0,
                       (void*)xg, (long)GDIM, 0);
    // 2) GRU layer 0 (persistent, batch-sliced, reg-prefetched weights)
    hipLaunchKernelGGL(k_pack_bat, dim3(256), dim3(256), 0, stream, w_hh0, wRZ0, wN0);
    hipLaunchKernelGGL(k_gru_batch3, dim3(256), dim3(512), 0, stream,
                       xg, h0, wRZ0, wN0, b_hh0);
    // 3) layer-1 input gates
    hipLaunchKernelGGL((k_gemm4<HID, 0, true, true, true>), dim3(400, 6), dim3(256), 0, stream,
                       (const void*)h0, (long)HID, 0, nullptr, nullptr, nn,
                       w_ih1, HID, 0L, b_ih1, (void*)xg, (long)GDIM, 0);
    // 4) GRU layer 1 (weights into dead h0 region)
    hipLaunchKernelGGL(k_pack_bat, dim3(256), dim3(256), 0, stream, w_hh1, wRZ1, wN1);
    hipLaunchKernelGGL(k_gru_batch3, dim3(256), dim3(512), 0, stream,
                       xg, h1, wRZ1, wN1, b_hh1);
    // 5) fused (proj @ attn_in_w), then masked qkv directly from h1
    hipLaunchKernelGGL(k_wq, dim3(768), dim3(256), 0, stream, attn_in_w, proj, WQ);
    hipLaunchKernelGGL((k_gemm4<HID, 2, true, false, true>), dim3(400, 6), dim3(256), 0, stream,
                       (const void*)h1, (long)HID, 0, nullptr, nullptr, nn,
                       WQ, HID, 0L, attn_in_b, (void*)qkv, (long)GDIM, 0);
    // 6) M precompute + single fused G GEMM (grid.z = head)
    hipLaunchKernelGGL(k_m, dim3(256), dim3(256), 0, stream, attn_out_w, mlp_w1, M);
    hipLaunchKernelGGL(k_const, dim3(1), dim3(256), 0, stream, attn_out_b, mlp_w1, mlp_b1, cbf);
    hipLaunchKernelGGL((k_gemm4<HD, 0, false, false, false>), dim3(400, 2, 4), dim3(256), 0, stream,
                       (const void*)(qkv + 2 * HID), (long)GDIM, HD, nullptr, nullptr, nn,
                       M, HD, (long)(HID * HD), (const float*)nullptr,
                       (void*)G, 1024L, HID);
    // 7) pairs
    hipLaunchKernelGGL(k_pairs3, dim3(BB * (NMAX - 1)), dim3(256), 0, stream,
                       qkv, G, cbf, nn, gum, mlp_w2, mlp_b2, adj);
}

// Round 9
// 2242.765 us; speedup vs baseline: 3.8084x; 3.5942x over previous
//
#include <hip/hip_runtime.h>
#include <hip/hip_bf16.h>
#include <math.h>

#define BB 512
#define LATENT 128
#define HID 256
#define GDIM 768
#define NMAX 50
#define NHEADS 4
#define HD 64
#define NPAIRS 1225

// ---------------------------------------------------------------------------
// Tiled GEMM, double-buffered LDS: O[r][oc] = sum_k X[r][k]*W[oc][k] (+bias)
// Block tile 64x128, 256 threads, thread tile 4x8, f64 accumulate.
// XMODE: 0 = plain X; 1 = X = masked(z+pos); 2 = X f64 with row mask n<nn[b]
template<int KD, int XMODE, bool XF64, bool OF64, bool BIAS>
__global__ __launch_bounds__(256) void k_gemm4(
        const void* __restrict__ Xv, long xstride, int xzoff,
        const float* __restrict__ zin, const float* __restrict__ pin,
        const int* __restrict__ nn,
        const float* __restrict__ W, int wstride, long wzoff,
        const float* __restrict__ bias,
        void* __restrict__ Ov, long ostride, int ozoff)
{
    __shared__ double xs[2][64][17];
    __shared__ float  wsm[2][128][17];
    const int rb = blockIdx.x * 64;
    const int ob = blockIdx.y * 128;
    const int zid = blockIdx.z;
    const int tid = threadIdx.x;
    const int ty = tid >> 4, tx = tid & 15;
    const int lr  = tid >> 2;            // X tile row 0..63
    const int lk  = (tid & 3) * 4;       // X k offset 0,4,8,12
    const int lr2 = tid >> 1;            // W tile row 0..127
    const int lk2 = (tid & 1) * 8;       // W k offset 0/8
    const int xrow = rb + lr;

    bool maskv = true;
    const float* zp = nullptr; const float* pp = nullptr;
    const double* xp64 = nullptr; const float* xp32 = nullptr;
    if (XMODE == 1) {
        int b = xrow / NMAX, t = xrow % NMAX;
        maskv = t < nn[b];
        zp = zin + (size_t)b * LATENT;
        pp = pin + (size_t)t * LATENT;
    } else if (XMODE == 2) {
        int b = xrow / NMAX, t = xrow % NMAX;
        maskv = t < nn[b];
        xp64 = (const double*)Xv + (size_t)xrow * xstride + zid * (long)xzoff;
    } else {
        if (XF64) xp64 = (const double*)Xv + (size_t)xrow * xstride + zid * (long)xzoff;
        else      xp32 = (const float*)Xv + (size_t)xrow * xstride + zid * (long)xzoff;
    }
    const float* wp = W + (size_t)zid * wzoff + (size_t)(ob + lr2) * wstride + lk2;

    double xstg[4]; float wstg[8];

#define GEMM_LOAD(K0)                                                          \
    {                                                                          \
        if (XMODE == 1) {                                                      \
            _Pragma("unroll")                                                  \
            for (int u = 0; u < 4; ++u)                                        \
                xstg[u] = maskv ? (double)zp[(K0) + lk + u]                    \
                                + (double)pp[(K0) + lk + u] : 0.0;             \
        } else if (XMODE == 2) {                                               \
            _Pragma("unroll")                                                  \
            for (int u = 0; u < 4; ++u)                                        \
                xstg[u] = maskv ? xp64[(K0) + lk + u] : 0.0;                   \
        } else if (XF64) {                                                     \
            _Pragma("unroll")                                                  \
            for (int u = 0; u < 4; ++u) xstg[u] = xp64[(K0) + lk + u];         \
        } else {                                                               \
            _Pragma("unroll")                                                  \
            for (int u = 0; u < 4; ++u) xstg[u] = (double)xp32[(K0) + lk + u]; \
        }                                                                      \
        _Pragma("unroll")                                                      \
        for (int u = 0; u < 8; ++u) wstg[u] = wp[(K0) + u];                    \
    }

#define GEMM_WRITE(BUF)                                                        \
    {                                                                          \
        _Pragma("unroll")                                                      \
        for (int u = 0; u < 4; ++u) xs[(BUF)][lr][lk + u] = xstg[u];           \
        _Pragma("unroll")                                                      \
        for (int u = 0; u < 8; ++u) wsm[(BUF)][lr2][lk2 + u] = wstg[u];        \
    }

    double acc[4][8];
    #pragma unroll
    for (int i = 0; i < 4; ++i)
        #pragma unroll
        for (int j = 0; j < 8; ++j) acc[i][j] = 0.0;

    constexpr int NC = KD / 16;
    GEMM_LOAD(0);
    GEMM_WRITE(0);
    for (int c = 0; c < NC; ++c) {
        __syncthreads();
        if (c + 1 < NC) GEMM_LOAD((c + 1) * 16);
        const int bi = c & 1;
        #pragma unroll
        for (int kk = 0; kk < 16; ++kk) {
            double wv[8];
            #pragma unroll
            for (int j = 0; j < 8; ++j) wv[j] = (double)wsm[bi][j * 16 + tx][kk];
            #pragma unroll
            for (int i = 0; i < 4; ++i) {
                double xr = xs[bi][ty * 4 + i][kk];
                #pragma unroll
                for (int j = 0; j < 8; ++j) acc[i][j] += xr * wv[j];
            }
        }
        if (c + 1 < NC) GEMM_WRITE((c + 1) & 1);
    }
    #pragma unroll
    for (int i = 0; i < 4; ++i) {
        size_t row = rb + ty * 4 + i;
        #pragma unroll
        for (int j = 0; j < 8; ++j) {
            int ocg = ob + j * 16 + tx;
            double v = acc[i][j];
            if (BIAS) v += (double)bias[ocg];
            size_t o = row * ostride + (size_t)zid * ozoff + ocg;
            if (OF64) ((double*)Ov)[o] = v;
            else      ((float*)Ov)[o] = (float)v;
        }
    }
#undef GEMM_LOAD
#undef GEMM_WRITE
}

// ---------------------------------------------------------------------------
// Ap[t][g] = sum_i pos[t][i] * w_ih0[g][i]   (50 x 768, f64, no bias)
__global__ __launch_bounds__(256) void k_ap(
        const float* __restrict__ pos, const float* __restrict__ w,
        double* __restrict__ Ap)
{
    __shared__ float ps[LATENT];
    const int t = blockIdx.x;
    const int tid = threadIdx.x;
    if (tid < LATENT) ps[tid] = pos[(size_t)t * LATENT + tid];
    __syncthreads();
    for (int g = tid; g < GDIM; g += 256) {
        double acc = 0.0;
        const float* wr = w + (size_t)g * LATENT;
        for (int i = 0; i < LATENT; ++i) acc += (double)ps[i] * (double)wr[i];
        Ap[(size_t)t * GDIM + g] = acc;
    }
}

// ---------------------------------------------------------------------------
// pack w_hh f32 [768][256] -> wRZ float2 [k][f] (r,z) and wN float [k][f]
__global__ __launch_bounds__(256) void k_pack_bat(
        const float* __restrict__ whh, float2* __restrict__ wRZ,
        float* __restrict__ wN)
{
    int k = blockIdx.x, f = threadIdx.x;
    float r = whh[(size_t)(0 * HID + f) * HID + k];
    float zz = whh[(size_t)(1 * HID + f) * HID + k];
    float n = whh[(size_t)(2 * HID + f) * HID + k];
    wRZ[(size_t)k * HID + f] = make_float2(r, zz);
    wN[(size_t)k * HID + f] = n;
}

// ---------------------------------------------------------------------------
// Persistent batch-sliced GRU (R6-proven structure, unroll 8).
// grid 256 x 512 threads; block owns 2 batches; h in LDS; weights stream L2.
// XGMODE 0: read xg[b,t,g] (layer 1).
// XGMODE 1: x-gates = (t<nn[b] ? Az[b][g]+Ap[t][g] : 0) + b_ih[g] (layer 0).
template<int XGMODE>
__global__ __launch_bounds__(512) void k_gru(
        const double* __restrict__ xg,            // XGMODE0: xg; XGMODE1: Az
        const double* __restrict__ Ap,
        const float* __restrict__ bih,
        const int* __restrict__ nn,
        double* __restrict__ hout,
        const float2* __restrict__ wRZ, const float* __restrict__ wN,
        const float* __restrict__ bhh)
{
    const int tid = threadIdx.x;
    const int f  = tid & 255;
    const int kq = tid >> 8;             // 0/1
    const int b0 = blockIdx.x * 2;

    __shared__ double hs[HID][2];        // [k][batch]
    __shared__ double red[HID][6];       // kq=1 partials

    { double* hf = &hs[0][0]; hf[tid] = 0.0; }

    double br = 0, bz = 0, bn = 0;
    double bihr = 0, bihz = 0, bihn = 0;
    int nn0 = 0, nn1 = 0;
    if (!kq) {
        br = (double)bhh[f]; bz = (double)bhh[HID + f]; bn = (double)bhh[2 * HID + f];
        if (XGMODE == 1) {
            bihr = (double)bih[f]; bihz = (double)bih[HID + f]; bihn = (double)bih[2 * HID + f];
            nn0 = nn[b0]; nn1 = nn[b0 + 1];
        }
    }
    const float2* wrz = wRZ + (size_t)(kq * 128) * HID + f;
    const float*  wn  = wN  + (size_t)(kq * 128) * HID + f;
    // XGMODE0: per (b,t) rows; XGMODE1: Az rows per batch
    const double* x0base = xg + (size_t)b0 * (XGMODE == 1 ? GDIM : NMAX * GDIM) + f;
    const double* x1base = xg + (size_t)(b0 + 1) * (XGMODE == 1 ? GDIM : NMAX * GDIM) + f;
    double* h0out = hout + (size_t)b0 * NMAX * HID + f;
    double* h1out = hout + (size_t)(b0 + 1) * NMAX * HID + f;
    const int kbase = kq * 128;

    __syncthreads();

    for (int t = 0; t < NMAX; ++t) {
        // x-gate values (kq0 only), issued early
        double xr0 = 0, xz0 = 0, xn0 = 0, xr1 = 0, xz1 = 0, xn1 = 0;
        if (!kq) {
            if (XGMODE == 0) {
                const double* x0 = x0base + (size_t)t * GDIM;
                const double* x1 = x1base + (size_t)t * GDIM;
                xr0 = x0[0]; xz0 = x0[HID]; xn0 = x0[2 * HID];
                xr1 = x1[0]; xz1 = x1[HID]; xn1 = x1[2 * HID];
            } else {
                const double* ap = Ap + (size_t)t * GDIM + f;
                double apr = ap[0], apz = ap[HID], apn = ap[2 * HID];
                if (t < nn0) {
                    xr0 = x0base[0] + apr; xz0 = x0base[HID] + apz; xn0 = x0base[2 * HID] + apn;
                }
                if (t < nn1) {
                    xr1 = x1base[0] + apr; xz1 = x1base[HID] + apz; xn1 = x1base[2 * HID] + apn;
                }
                xr0 += bihr; xz0 += bihz; xn0 += bihn;
                xr1 += bihr; xz1 += bihz; xn1 += bihn;
            }
        }

        double ar0 = 0, az0 = 0, an0 = 0, ar1 = 0, az1 = 0, an1 = 0;
        #pragma unroll 8
        for (int kk = 0; kk < 128; ++kk) {
            float2 rz = wrz[(size_t)kk * HID];
            float  nw = wn[(size_t)kk * HID];
            double wrd = (double)rz.x, wzd = (double)rz.y, wnd = (double)nw;
            double h0k = hs[kbase + kk][0];
            double h1k = hs[kbase + kk][1];
            ar0 += h0k * wrd; az0 += h0k * wzd; an0 += h0k * wnd;
            ar1 += h1k * wrd; az1 += h1k * wzd; an1 += h1k * wnd;
        }
        if (kq) {
            red[f][0] = ar0; red[f][1] = az0; red[f][2] = an0;
            red[f][3] = ar1; red[f][4] = az1; red[f][5] = an1;
        }
        __syncthreads();
        if (!kq) {
            ar0 += red[f][0]; az0 += red[f][1]; an0 += red[f][2];
            ar1 += red[f][3]; az1 += red[f][4]; an1 += red[f][5];
            double hp0 = hs[f][0], hp1 = hs[f][1];
            double rg0 = 1.0 / (1.0 + exp(-(xr0 + ar0 + br)));
            double zg0 = 1.0 / (1.0 + exp(-(xz0 + az0 + bz)));
            double ng0 = tanh(xn0 + rg0 * (an0 + bn));
            double h0n = (1.0 - zg0) * ng0 + zg0 * hp0;
            double rg1 = 1.0 / (1.0 + exp(-(xr1 + ar1 + br)));
            double zg1 = 1.0 / (1.0 + exp(-(xz1 + az1 + bz)));
            double ng1 = tanh(xn1 + rg1 * (an1 + bn));
            double h1n = (1.0 - zg1) * ng1 + zg1 * hp1;
            hs[f][0] = h0n; hs[f][1] = h1n;
            h0out[(size_t)t * HID] = h0n;
            h1out[(size_t)t * HID] = h1n;
        }
        __syncthreads();
    }
}

// ---------------------------------------------------------------------------
// WQ[g][h] = sum_o attn_in_w[g][o] * proj[o][h]   (768x256 f32)
__global__ __launch_bounds__(256) void k_wq(
        const float* __restrict__ aiw, const float* __restrict__ proj,
        float* __restrict__ WQ)
{
    __shared__ float arow[HID];
    int g = blockIdx.x, h = threadIdx.x;
    arow[h] = aiw[(size_t)g * HID + h];
    __syncthreads();
    double acc = 0.0;
    for (int o = 0; o < HID; ++o) acc += (double)arow[o] * (double)proj[(size_t)o * HID + h];
    WQ[(size_t)g * HID + h] = (float)acc;
}

// M[h][k][d] = sum_m wo[m][h*64+d] * w1[k][m]   (4x256x64 f32)
__global__ __launch_bounds__(256) void k_m(
        const float* __restrict__ wo, const float* __restrict__ w1,
        float* __restrict__ M)
{
    __shared__ float w1row[HID];
    int k = blockIdx.x, hd = threadIdx.x;
    w1row[hd] = w1[(size_t)k * HID + hd];
    __syncthreads();
    double acc = 0.0;
    for (int m = 0; m < HID; ++m) acc += (double)w1row[m] * (double)wo[(size_t)m * HID + hd];
    M[(((size_t)(hd >> 6)) * HID + k) * HD + (hd & 63)] = (float)acc;
}

// c[k] = sum_m attn_out_b[m]*mlp_w1[k,m] + mlp_b1[k]
__global__ void k_const(const float* __restrict__ ob, const float* __restrict__ w1,
                        const float* __restrict__ b1, double* __restrict__ c)
{
    int k = threadIdx.x;
    double acc = 0.0;
    for (int m = 0; m < HID; ++m) acc += (double)ob[m] * (double)w1[k * HID + m];
    c[k] = acc + (double)b1[k];
}

// ---------------------------------------------------------------------------
// Pairs: block per (b,i); wave per j (stride 4). G unified [row][h*256+k].
__global__ __launch_bounds__(256) void k_pairs3(
        const float* __restrict__ QKV, const float* __restrict__ G,
        const double* __restrict__ c,
        const int* __restrict__ nn, const float* __restrict__ gum,
        const float* __restrict__ w2, const float* __restrict__ b2,
        float* __restrict__ adj)
{
    const int bi = blockIdx.x;
    const int b = bi / (NMAX - 1);
    const int i = bi % (NMAX - 1);
    const int nnb = nn[b];
    if (i >= nnb - 1) return;
    const int tid = threadIdx.x;
    const int lane = tid & 63;
    const int wave = tid >> 6;
    const size_t rowi = (size_t)b * NMAX + i;

    double cw[4], w2r[4];
    float gir[4][4];
    #pragma unroll
    for (int q = 0; q < 4; ++q) {
        int k = lane + 64 * q;
        cw[q] = c[k];
        w2r[q] = (double)w2[k] - (double)w2[HID + k];
        #pragma unroll
        for (int h = 0; h < 4; ++h) gir[q][h] = G[rowi * 1024 + h * HID + k];
    }
    const int sh = lane >> 4, sd = (lane & 15) * 4;
    const float4 qv  = *(const float4*)&QKV[rowi * GDIM + sh * HD + sd];
    const float4 kv0 = *(const float4*)&QKV[rowi * GDIM + HID + sh * HD + sd];
    double s0 = (double)qv.x * kv0.x + (double)qv.y * kv0.y
              + (double)qv.z * kv0.z + (double)qv.w * kv0.w;
    #pragma unroll
    for (int m = 1; m < 16; m <<= 1) s0 += __shfl_xor(s0, m, 64);
    s0 *= 0.125;
    const double b2d = (double)b2[0] - (double)b2[1];

    for (int j = i + 1 + wave; j < nnb; j += 4) {
        const size_t rowj = (size_t)b * NMAX + j;
        const float4 kv = *(const float4*)&QKV[rowj * GDIM + HID + sh * HD + sd];
        double s1 = (double)qv.x * kv.x + (double)qv.y * kv.y
                  + (double)qv.z * kv.z + (double)qv.w * kv.w;
        #pragma unroll
        for (int m = 1; m < 16; m <<= 1) s1 += __shfl_xor(s1, m, 64);
        s1 *= 0.125;
        double mx = fmax(s0, s1);
        double e0 = exp(s0 - mx), e1 = exp(s1 - mx);
        double inv = 1.0 / (e0 + e1);
        double a0 = e0 * inv, a1 = e1 * inv;
        double a0h[4], a1h[4];
        #pragma unroll
        for (int h = 0; h < 4; ++h) {
            a0h[h] = __shfl(a0, h * 16, 64);
            a1h[h] = __shfl(a1, h * 16, 64);
        }
        double dsum = 0.0;
        #pragma unroll
        for (int q = 0; q < 4; ++q) {
            int k = lane + 64 * q;
            double pre = cw[q];
            #pragma unroll
            for (int h = 0; h < 4; ++h)
                pre += a0h[h] * (double)gir[q][h]
                     + a1h[h] * (double)G[rowj * 1024 + h * HID + k];
            if (pre > 0.0) dsum += pre * w2r[q];
        }
        #pragma unroll
        for (int m = 1; m < 64; m <<= 1) dsum += __shfl_xor(dsum, m, 64);
        if (lane == 0) {
            int p_idx = i * (2 * NMAX - i - 1) / 2 + (j - i - 1);
            const float* gp = gum + ((size_t)b * NPAIRS + p_idx) * 2;
            double d = dsum + b2d + (double)gp[0] - (double)gp[1];
            if (d >= 0.0) {
                adj[(size_t)b * NMAX * NMAX + i * NMAX + j] = 1.0f;
                adj[(size_t)b * NMAX * NMAX + j * NMAX + i] = 1.0f;
            }
        }
    }
}

__global__ void k_ws_too_small(float* adj) { adj[0] = 2.0f; }

// ---------------------------------------------------------------------------
extern "C" void kernel_launch(void* const* d_in, const int* in_sizes, int n_in,
                              void* d_out, int out_size, void* d_ws, size_t ws_size,
                              hipStream_t stream)
{
    const float* z          = (const float*)d_in[0];
    const int*   nn         = (const int*)d_in[1];
    const float* pos        = (const float*)d_in[3];
    const float* w_ih0      = (const float*)d_in[4];
    const float* w_hh0      = (const float*)d_in[5];
    const float* b_ih0      = (const float*)d_in[6];
    const float* b_hh0      = (const float*)d_in[7];
    const float* w_ih1      = (const float*)d_in[8];
    const float* w_hh1      = (const float*)d_in[9];
    const float* b_ih1      = (const float*)d_in[10];
    const float* b_hh1      = (const float*)d_in[11];
    const float* proj       = (const float*)d_in[12];
    const float* attn_in_w  = (const float*)d_in[13];
    const float* attn_in_b  = (const float*)d_in[14];
    const float* attn_out_w = (const float*)d_in[15];
    const float* attn_out_b = (const float*)d_in[16];
    const float* mlp_w1     = (const float*)d_in[17];
    const float* mlp_b1     = (const float*)d_in[18];
    const float* mlp_w2     = (const float*)d_in[19];
    const float* mlp_b2     = (const float*)d_in[20];
    const float* gum        = (const float*)d_in[21];

    float* adj = (float*)d_out;
    hipMemsetAsync(adj, 0, (size_t)out_size * sizeof(float), stream);

    const size_t NEED = 262144000;
    if (ws_size < NEED) { hipLaunchKernelGGL(k_ws_too_small, dim3(1), dim3(1), 0, stream, adj); return; }

    // Region map (phase-aliased, single stream => sequential hazards OK):
    //  A [0,157286400):  Az f64 @0 (3.1MB) + Ap f64 @3145728 (0.3MB) during GRU0
    //                    | then xg f64 (whole A, overwrites dead Az/Ap)
    //                    | post-GRU: qkv f32 @0, G f32 @78643200
    //  B [157286400,209715200): h0 f64 | post-xg1: wRZ1 @B, wN1 @B+524288
    //                    | post-G-spill tail: WQ @183500800, M @184287232,
    //                      cbf @184549376
    //  C [209715200,262144000): wRZ0 @C, wN0 @C+524288 | post-gru0: h1 f64 @C
    char* ws = (char*)d_ws;
    const size_t Boff = 157286400, Coff = 209715200;
    double* Az   = (double*)(ws);
    double* Ap   = (double*)(ws + 3145728);
    double* xg   = (double*)(ws);
    double* h0   = (double*)(ws + Boff);
    double* h1   = (double*)(ws + Coff);
    float2* wRZ0 = (float2*)(ws + Coff);
    float*  wN0  = (float*)(ws + Coff + 524288);
    float2* wRZ1 = (float2*)(ws + Boff);
    float*  wN1  = (float*)(ws + Boff + 524288);
    float*  qkv  = (float*)(ws);
    float*  G    = (float*)(ws + 78643200);
    float*  WQ   = (float*)(ws + 183500800);
    float*  M    = (float*)(ws + 184287232);
    double* cbf  = (double*)(ws + 184549376);

    // 1) separable layer-0 input gates: Az = z@w_ih0^T (512x768), Ap = pos@w_ih0^T
    hipLaunchKernelGGL((k_gemm4<LATENT, 0, false, true, false>), dim3(8, 6), dim3(256), 0, stream,
                       (const void*)z, (long)LATENT, 0, nullptr, nullptr, nn,
                       w_ih0, LATENT, 0L, (const float*)nullptr,
                       (void*)Az, (long)GDIM, 0);
    hipLaunchKernelGGL(k_ap, dim3(NMAX), dim3(256), 0, stream, pos, w_ih0, Ap);
    // 2) GRU layer 0 (fused x-gates from Az+Ap, masked, + b_ih0)
    hipLaunchKernelGGL(k_pack_bat, dim3(256), dim3(256), 0, stream, w_hh0, wRZ0, wN0);
    hipLaunchKernelGGL((k_gru<1>), dim3(256), dim3(512), 0, stream,
                       Az, Ap, b_ih0, nn, h0, wRZ0, wN0, b_hh0);
    // 3) layer-1 input gates (full GEMM from h0)
    hipLaunchKernelGGL((k_gemm4<HID, 0, true, true, true>), dim3(400, 6), dim3(256), 0, stream,
                       (const void*)h0, (long)HID, 0, nullptr, nullptr, nn,
                       w_ih1, HID, 0L, b_ih1, (void*)xg, (long)GDIM, 0);
    // 4) GRU layer 1 (weights into dead h0 region)
    hipLaunchKernelGGL(k_pack_bat, dim3(256), dim3(256), 0, stream, w_hh1, wRZ1, wN1);
    hipLaunchKernelGGL((k_gru<0>), dim3(256), dim3(512), 0, stream,
                       xg, nullptr, nullptr, nn, h1, wRZ1, wN1, b_hh1);
    // 5) fused (proj @ attn_in_w), then masked qkv directly from h1
    hipLaunchKernelGGL(k_wq, dim3(768), dim3(256), 0, stream, attn_in_w, proj, WQ);
    hipLaunchKernelGGL((k_gemm4<HID, 2, true, false, true>), dim3(400, 6), dim3(256), 0, stream,
                       (const void*)h1, (long)HID, 0, nullptr, nullptr, nn,
                       WQ, HID, 0L, attn_in_b, (void*)qkv, (long)GDIM, 0);
    // 6) M precompute + single fused G GEMM (grid.z = head)
    hipLaunchKernelGGL(k_m, dim3(256), dim3(256), 0, stream, attn_out_w, mlp_w1, M);
    hipLaunchKernelGGL(k_const, dim3(1), dim3(256), 0, stream, attn_out_b, mlp_w1, mlp_b1, cbf);
    hipLaunchKernelGGL((k_gemm4<HD, 0, false, false, false>), dim3(400, 2, 4), dim3(256), 0, stream,
                       (const void*)(qkv + 2 * HID), (long)GDIM, HD, nullptr, nullptr, nn,
                       M, HD, (long)(HID * HD), (const float*)nullptr,
                       (void*)G, 1024L, HID);
    // 7) pairs
    hipLaunchKernelGGL(k_pairs3, dim3(BB * (NMAX - 1)), dim3(256), 0, stream,
                       qkv, G, cbf, nn, gum, mlp_w2, mlp_b2, adj);
}